// Round 10
// baseline (1074.389 us; speedup 1.0000x reference)
//
#include <hip/hip_runtime.h>
#include <math.h>

// ---------------------------------------------------------------------------
// GINE 2-layer GNN, N=100K nodes (D 32->64->64), E=3.2M edges, ED=16.
// Round 10: R9's 0.121 failure attributed to We1->bf16: layer-1 systematic
// error is amplified ~32x by layer-2's sum aggregation (same mechanism as
// R6's h1-bf16 failure). Error budget rule: layer-1 path (x, We1, h1) stays
// fp32; layer-2 edge path (ea, We2) may be bf16 (R8: 3.9e-3).
//   agg1_bf = R8's proven unpack+fmaf kernel (fp32 We1), launch_bounds(256,4)
//   agg2_bf = SGPR-dot2 kernel at launch_bounds(256,8)  [R9, math==R8]
//   scatter = perm-scatter (4B tokens) + sequential materialize [R9]
// ---------------------------------------------------------------------------

#define IMIN(a, b) ((a) < (b) ? (a) : (b))

__device__ __forceinline__ unsigned short f2bf(float f) {
  unsigned int u = __float_as_uint(f);
  u += 0x7FFFu + ((u >> 16) & 1u);
  return (unsigned short)(u >> 16);
}
__device__ __forceinline__ float bflo(int w) {
  return __uint_as_float(((unsigned int)w) << 16);
}
__device__ __forceinline__ float bfhi(int w) {
  return __uint_as_float(((unsigned int)w) & 0xFFFF0000u);
}
// D = a.bf16[0]*b.bf16[0] + a.bf16[1]*b.bf16[1] + c ; a is wave-uniform SGPR
__device__ __forceinline__ float dot2bf_s(unsigned a, unsigned b, float c) {
  float r;
  asm("v_dot2_f32_bf16 %0, %1, %2, %3" : "=v"(r) : "s"(a), "v"(b), "v"(c));
  return r;
}

// ============================ sort pipeline ================================

__global__ __launch_bounds__(256) void k_hist(
    const int* __restrict__ dst, int* __restrict__ count, int E)
{
  for (int e = blockIdx.x * blockDim.x + threadIdx.x; e < E;
       e += gridDim.x * blockDim.x)
    atomicAdd(&count[dst[e]], 1);
}

__global__ __launch_bounds__(256) void k_scan1(
    const int* __restrict__ cnt, int* __restrict__ exc,
    int* __restrict__ bsum, int M)
{
  __shared__ int wtot[4];
  const int t = threadIdx.x, lane = t & 63, wv = t >> 6;
  const int base = blockIdx.x * 1024 + t * 4;
  const int v0 = (base + 0 < M) ? cnt[base + 0] : 0;
  const int v1 = (base + 1 < M) ? cnt[base + 1] : 0;
  const int v2 = (base + 2 < M) ? cnt[base + 2] : 0;
  const int v3 = (base + 3 < M) ? cnt[base + 3] : 0;
  const int tsum = v0 + v1 + v2 + v3;
  int x = tsum;
#pragma unroll
  for (int off = 1; off < 64; off <<= 1) {
    const int y = __shfl_up(x, off, 64);
    if (lane >= off) x += y;
  }
  if (lane == 63) wtot[wv] = x;
  __syncthreads();
  int woff = 0;
#pragma unroll
  for (int w = 0; w < 4; ++w)
    if (w < wv) woff += wtot[w];
  int run = woff + x - tsum;
  if (base + 0 < M) exc[base + 0] = run;
  run += v0;
  if (base + 1 < M) exc[base + 1] = run;
  run += v1;
  if (base + 2 < M) exc[base + 2] = run;
  run += v2;
  if (base + 3 < M) exc[base + 3] = run;
  if (t == 255) bsum[blockIdx.x] = woff + x;
}

__global__ void k_scan2(int* __restrict__ bsum, int nb)
{
  if (threadIdx.x == 0) {
    int r = 0;
    for (int i = 0; i < nb; ++i) { const int t = bsum[i]; bsum[i] = r; r += t; }
  }
}

__global__ __launch_bounds__(256) void k_scan3(
    int* __restrict__ start, int* __restrict__ cursor,
    const int* __restrict__ bsum, int M)
{
  for (int i = blockIdx.x * blockDim.x + threadIdx.x; i < M;
       i += gridDim.x * blockDim.x) {
    const int s = start[i] + bsum[i >> 10];
    start[i] = s;
    cursor[i] = s;
  }
}

// random part: 4B tokens only (perm footprint 12.8MB, L2/L3-absorbed)
__global__ __launch_bounds__(256) void k_scatter_perm(
    const int* __restrict__ dst, int* __restrict__ cursor,
    int* __restrict__ perm, int E)
{
  for (int e = blockIdx.x * blockDim.x + threadIdx.x; e < E;
       e += gridDim.x * blockDim.x) {
    const int pos = atomicAdd(&cursor[dst[e]], 1);
    perm[pos] = e;
  }
}

// sequential materialize: streaming writes of eas (bf16) + srcs.
__global__ __launch_bounds__(256) void k_mat_bf(
    const int* __restrict__ perm, const int* __restrict__ src,
    const float4* __restrict__ ea4, int* __restrict__ srcs,
    uint2* __restrict__ easH, int E)
{
  const long tid0 = (long)blockIdx.x * blockDim.x + threadIdx.x;
  const long stride = (long)gridDim.x * blockDim.x;
  const int sub = threadIdx.x & 3;
  const long total = (long)E * 4;
  for (long t = tid0; t < total; t += stride) {
    const int pos = (int)(t >> 2);
    const int e = perm[pos];
    if (sub == 0) srcs[pos] = src[e];
    const float4 v = ea4[(size_t)e * 4 + sub];
    uint2 w;
    w.x = (unsigned)f2bf(v.x) | ((unsigned)f2bf(v.y) << 16);
    w.y = (unsigned)f2bf(v.z) | ((unsigned)f2bf(v.w) << 16);
    easH[(size_t)pos * 4 + sub] = w;
  }
}

// ============ fused edge-embed + aggregate (bf16 eas) ======================

// agg2: SGPR-fed v_dot2_f32_bf16 (We2 bf16 is in-budget), 8 waves/SIMD.
__global__ __launch_bounds__(256, 8) void k_agg2_bf(
    const float* __restrict__ h1, const int4* __restrict__ EH,
    const int* __restrict__ srcs, const int* __restrict__ start,
    const float* __restrict__ We, const float* __restrict__ be,
    float* __restrict__ aggr, int N)
{
  const int lane = threadIdx.x & 63;
  unsigned wcolp[8];
#pragma unroll
  for (int c = 0; c < 8; ++c)
    wcolp[c] = (unsigned)f2bf(We[(2 * c) * 64 + lane]) |
               ((unsigned)f2bf(We[(2 * c + 1) * 64 + lane]) << 16);
  const float bias = be[lane];
  const int wid = (blockIdx.x * blockDim.x + threadIdx.x) >> 6;
  const int nw = (gridDim.x * blockDim.x) >> 6;
  for (int d = wid; d < N; d += nw) {
    const int beg = __builtin_amdgcn_readfirstlane(start[d]);
    const int end = __builtin_amdgcn_readfirstlane(start[d + 1]);
    float acc = 0.f;
    if (beg < end) {
      const int em1 = end - 1;
      int4 evA[4][2], evB[4][2];
      float hvA[4], hvB[4];
      int sB[4], sC[4];
      {
        int sA[4];
#pragma unroll
        for (int q = 0; q < 4; ++q) {
          const int c = IMIN(beg + q, em1);
          sA[q] = srcs[c];
          evA[q][0] = EH[(size_t)c * 2 + 0];
          evA[q][1] = EH[(size_t)c * 2 + 1];
        }
#pragma unroll
        for (int q = 0; q < 4; ++q) hvA[q] = h1[(size_t)sA[q] * 64 + lane];
#pragma unroll
        for (int q = 0; q < 4; ++q) {
          const int c = IMIN(beg + 4 + q, em1);
          sB[q] = srcs[c];
        }
      }
      for (int i = beg; i < end; i += 4) {
        const bool inB = (i + 4) < end;
        if (inB) {
#pragma unroll
          for (int q = 0; q < 4; ++q) {
            const int c = IMIN(i + 4 + q, em1);
            evB[q][0] = EH[(size_t)c * 2 + 0];
            evB[q][1] = EH[(size_t)c * 2 + 1];
          }
#pragma unroll
          for (int q = 0; q < 4; ++q) hvB[q] = h1[(size_t)sB[q] * 64 + lane];
#pragma unroll
          for (int q = 0; q < 4; ++q) {
            const int c = IMIN(i + 8 + q, em1);
            sC[q] = srcs[c];
          }
        } else {
#pragma unroll
          for (int q = 0; q < 4; ++q) {
            evB[q][0] = evA[q][0]; evB[q][1] = evA[q][1];
            hvB[q] = hvA[q]; sC[q] = sB[q];
          }
        }
        __builtin_amdgcn_sched_barrier(0);
#pragma unroll
        for (int q = 0; q < 4; ++q) {
          const int4 w0 = evA[q][0], w1 = evA[q][1];
          float m = bias;
          m = dot2bf_s((unsigned)w0.x, wcolp[0], m);
          m = dot2bf_s((unsigned)w0.y, wcolp[1], m);
          m = dot2bf_s((unsigned)w0.z, wcolp[2], m);
          m = dot2bf_s((unsigned)w0.w, wcolp[3], m);
          m = dot2bf_s((unsigned)w1.x, wcolp[4], m);
          m = dot2bf_s((unsigned)w1.y, wcolp[5], m);
          m = dot2bf_s((unsigned)w1.z, wcolp[6], m);
          m = dot2bf_s((unsigned)w1.w, wcolp[7], m);
          acc += (i + q < end) ? fmaxf(hvA[q] + m, 0.f) : 0.f;
        }
#pragma unroll
        for (int q = 0; q < 4; ++q) {
          evA[q][0] = evB[q][0]; evA[q][1] = evB[q][1];
          hvA[q] = hvB[q]; sB[q] = sC[q];
        }
      }
    }
    aggr[(size_t)d * 64 + lane] = acc;
  }
}

// agg1: R8's proven kernel — fp32 We1 (layer-1 error budget), bf16 ea unpack,
// half-wave split, 8 edges/iter.
__global__ __launch_bounds__(256, 4) void k_agg1_bf(
    const float* __restrict__ x, const int4* __restrict__ EH,
    const int* __restrict__ srcs, const int* __restrict__ start,
    const float* __restrict__ We, const float* __restrict__ be,
    float* __restrict__ aggr, int N)
{
  const int lane = threadIdx.x & 63;
  const int j = lane & 31;
  const int o = (lane >> 5) * 4;  // half-wave chain base within 8-block
  float wcol[16];
#pragma unroll
  for (int k = 0; k < 16; ++k) wcol[k] = We[k * 32 + j];
  const float bias = be[j];
  const int wid = (blockIdx.x * blockDim.x + threadIdx.x) >> 6;
  const int nw = (gridDim.x * blockDim.x) >> 6;
  for (int d = wid; d < N; d += nw) {
    const int beg = __builtin_amdgcn_readfirstlane(start[d]);
    const int end = __builtin_amdgcn_readfirstlane(start[d + 1]);
    float acc = 0.f;
    if (beg < end) {
      const int em1 = end - 1;
      int4 evA[4][2], evB[4][2];
      float hvA[4], hvB[4];
      int sB[4], sC[4];
      {
        int sA[4];
#pragma unroll
        for (int q = 0; q < 4; ++q) {
          const int c = IMIN(beg + o + q, em1);
          sA[q] = srcs[c];
          evA[q][0] = EH[(size_t)c * 2 + 0];
          evA[q][1] = EH[(size_t)c * 2 + 1];
        }
#pragma unroll
        for (int q = 0; q < 4; ++q) hvA[q] = x[(size_t)sA[q] * 32 + j];
#pragma unroll
        for (int q = 0; q < 4; ++q) {
          const int c = IMIN(beg + 8 + o + q, em1);
          sB[q] = srcs[c];
        }
      }
      for (int i = beg; i < end; i += 8) {
        const bool inB = (i + 8) < end;
        if (inB) {
#pragma unroll
          for (int q = 0; q < 4; ++q) {
            const int c = IMIN(i + 8 + o + q, em1);
            evB[q][0] = EH[(size_t)c * 2 + 0];
            evB[q][1] = EH[(size_t)c * 2 + 1];
          }
#pragma unroll
          for (int q = 0; q < 4; ++q) hvB[q] = x[(size_t)sB[q] * 32 + j];
#pragma unroll
          for (int q = 0; q < 4; ++q) {
            const int c = IMIN(i + 16 + o + q, em1);
            sC[q] = srcs[c];
          }
        } else {
#pragma unroll
          for (int q = 0; q < 4; ++q) {
            evB[q][0] = evA[q][0]; evB[q][1] = evA[q][1];
            hvB[q] = hvA[q]; sC[q] = sB[q];
          }
        }
        __builtin_amdgcn_sched_barrier(0);
#pragma unroll
        for (int q = 0; q < 4; ++q) {
          const int4 w0 = evA[q][0], w1 = evA[q][1];
          float m = bias;
          m = fmaf(bflo(w0.x), wcol[0],  m); m = fmaf(bfhi(w0.x), wcol[1],  m);
          m = fmaf(bflo(w0.y), wcol[2],  m); m = fmaf(bfhi(w0.y), wcol[3],  m);
          m = fmaf(bflo(w0.z), wcol[4],  m); m = fmaf(bfhi(w0.z), wcol[5],  m);
          m = fmaf(bflo(w0.w), wcol[6],  m); m = fmaf(bfhi(w0.w), wcol[7],  m);
          m = fmaf(bflo(w1.x), wcol[8],  m); m = fmaf(bfhi(w1.x), wcol[9],  m);
          m = fmaf(bflo(w1.y), wcol[10], m); m = fmaf(bfhi(w1.y), wcol[11], m);
          m = fmaf(bflo(w1.z), wcol[12], m); m = fmaf(bfhi(w1.z), wcol[13], m);
          m = fmaf(bflo(w1.w), wcol[14], m); m = fmaf(bfhi(w1.w), wcol[15], m);
          acc += (i + o + q < end) ? fmaxf(hvA[q] + m, 0.f) : 0.f;
        }
#pragma unroll
        for (int q = 0; q < 4; ++q) {
          evA[q][0] = evB[q][0]; evA[q][1] = evB[q][1];
          hvA[q] = hvB[q]; sB[q] = sC[q];
        }
      }
    }
    acc += __shfl(acc, lane ^ 32, 64);
    if (lane < 32) aggr[(size_t)d * 32 + j] = acc;
  }
}

// ================= mode-1 fallback (fp32 ea via perm) ======================

__global__ __launch_bounds__(256, 4) void k_agg2_f(
    const float* __restrict__ h1, const float* __restrict__ EA,
    const int* __restrict__ SRCS, const int* __restrict__ perm,
    const int* __restrict__ start, const float* __restrict__ We,
    const float* __restrict__ be, float* __restrict__ aggr, int N)
{
  const int lane = threadIdx.x & 63;
  float wcol[16];
#pragma unroll
  for (int k = 0; k < 16; ++k) wcol[k] = We[k * 64 + lane];
  const float bias = be[lane];
  const float4* EA4 = (const float4*)EA;
  const int wid = (blockIdx.x * blockDim.x + threadIdx.x) >> 6;
  const int nw = (gridDim.x * blockDim.x) >> 6;
  for (int d = wid; d < N; d += nw) {
    const int beg = __builtin_amdgcn_readfirstlane(start[d]);
    const int end = __builtin_amdgcn_readfirstlane(start[d + 1]);
    float acc = 0.f;
    for (int i = beg; i < end; ++i) {
      const int a = perm[i];
      const int s = SRCS[a];
      float4 ev[4];
#pragma unroll
      for (int c = 0; c < 4; ++c) ev[c] = EA4[(size_t)a * 4 + c];
      const float hv = h1[(size_t)s * 64 + lane];
      float m = bias;
#pragma unroll
      for (int c = 0; c < 4; ++c) {
        m = fmaf(ev[c].x, wcol[4 * c + 0], m);
        m = fmaf(ev[c].y, wcol[4 * c + 1], m);
        m = fmaf(ev[c].z, wcol[4 * c + 2], m);
        m = fmaf(ev[c].w, wcol[4 * c + 3], m);
      }
      acc += fmaxf(hv + m, 0.f);
    }
    aggr[(size_t)d * 64 + lane] = acc;
  }
}

__global__ __launch_bounds__(256, 4) void k_agg1_f(
    const float* __restrict__ x, const float* __restrict__ EA,
    const int* __restrict__ SRCS, const int* __restrict__ perm,
    const int* __restrict__ start, const float* __restrict__ We,
    const float* __restrict__ be, float* __restrict__ aggr, int N)
{
  const int lane = threadIdx.x & 63;
  const int j = lane & 31;
  const int p = lane >> 5;
  float wcol[16];
#pragma unroll
  for (int k = 0; k < 16; ++k) wcol[k] = We[k * 32 + j];
  const float bias = be[j];
  const float4* EA4 = (const float4*)EA;
  const int wid = (blockIdx.x * blockDim.x + threadIdx.x) >> 6;
  const int nw = (gridDim.x * blockDim.x) >> 6;
  for (int d = wid; d < N; d += nw) {
    const int beg = __builtin_amdgcn_readfirstlane(start[d]);
    const int end = __builtin_amdgcn_readfirstlane(start[d + 1]);
    float acc = 0.f;
    for (int i = beg + p; i < end; i += 2) {
      const int a = perm[i];
      const int s = SRCS[a];
      float4 ev[4];
#pragma unroll
      for (int c = 0; c < 4; ++c) ev[c] = EA4[(size_t)a * 4 + c];
      const float xv = x[(size_t)s * 32 + j];
      float m = bias;
#pragma unroll
      for (int c = 0; c < 4; ++c) {
        m = fmaf(ev[c].x, wcol[4 * c + 0], m);
        m = fmaf(ev[c].y, wcol[4 * c + 1], m);
        m = fmaf(ev[c].z, wcol[4 * c + 2], m);
        m = fmaf(ev[c].w, wcol[4 * c + 3], m);
      }
      acc += fmaxf(xv + m, 0.f);
    }
    acc += __shfl(acc, lane ^ 32, 64);
    if (lane < 32) aggr[(size_t)d * 32 + j] = acc;
  }
}

// ============================ node MLPs + head =============================

__global__ __launch_bounds__(256) void k_node1(
    const float* __restrict__ x, const float* __restrict__ aggr,
    const float* __restrict__ Wa, const float* __restrict__ ba,
    const float* __restrict__ Wb, const float* __restrict__ bb,
    float* __restrict__ h1, int N)
{
  __shared__ float hsh[4][32];
  __shared__ float tsh[4][64];
  const int lane = threadIdx.x & 63;
  const int wv = threadIdx.x >> 6;
  float wa[32], wb[64];
#pragma unroll
  for (int k = 0; k < 32; ++k) wa[k] = Wa[k * 64 + lane];
#pragma unroll
  for (int k = 0; k < 64; ++k) wb[k] = Wb[k * 64 + lane];
  const float ba_l = ba[lane], bb_l = bb[lane];
  const int wid = (blockIdx.x * blockDim.x + threadIdx.x) >> 6;
  const int nw = (gridDim.x * blockDim.x) >> 6;
  const float4* hp4 = (const float4*)(&hsh[wv][0]);
  const float4* tp = (const float4*)(&tsh[wv][0]);
  for (int n = wid; n < N; n += nw) {
    if (lane < 32)
      hsh[wv][lane] = x[(size_t)n * 32 + lane] + aggr[(size_t)n * 32 + lane];
    float t = ba_l;
#pragma unroll
    for (int c = 0; c < 8; ++c) {
      const float4 hv = hp4[c];
      t = fmaf(hv.x, wa[4 * c + 0], t);
      t = fmaf(hv.y, wa[4 * c + 1], t);
      t = fmaf(hv.z, wa[4 * c + 2], t);
      t = fmaf(hv.w, wa[4 * c + 3], t);
    }
    t = fmaxf(t, 0.f);
    tsh[wv][lane] = t;
    float h = bb_l;
#pragma unroll
    for (int c = 0; c < 16; ++c) {
      const float4 tv = tp[c];
      h = fmaf(tv.x, wb[4 * c + 0], h);
      h = fmaf(tv.y, wb[4 * c + 1], h);
      h = fmaf(tv.z, wb[4 * c + 2], h);
      h = fmaf(tv.w, wb[4 * c + 3], h);
    }
    h1[(size_t)n * 64 + lane] = h;
  }
}

__global__ __launch_bounds__(256) void k_node2(
    const float* __restrict__ h1, const float* __restrict__ aggr,
    const float* __restrict__ Wa, const float* __restrict__ ba,
    const float* __restrict__ Wb, const float* __restrict__ bb,
    float* __restrict__ gsum, int N)
{
  __shared__ float hsh[4][64];
  __shared__ float tsh[4][64];
  __shared__ float red[4][64];
  const int lane = threadIdx.x & 63;
  const int wv = threadIdx.x >> 6;
  float wa[64], wb[64];
#pragma unroll
  for (int k = 0; k < 64; ++k) wa[k] = Wa[k * 64 + lane];
#pragma unroll
  for (int k = 0; k < 64; ++k) wb[k] = Wb[k * 64 + lane];
  const float ba_l = ba[lane], bb_l = bb[lane];
  float psum = 0.f;
  const int wid = (blockIdx.x * blockDim.x + threadIdx.x) >> 6;
  const int nw = (gridDim.x * blockDim.x) >> 6;
  const float4* hp4 = (const float4*)(&hsh[wv][0]);
  const float4* tp = (const float4*)(&tsh[wv][0]);
  for (int n = wid; n < N; n += nw) {
    hsh[wv][lane] = h1[(size_t)n * 64 + lane] + aggr[(size_t)n * 64 + lane];
    float t = ba_l;
#pragma unroll
    for (int c = 0; c < 16; ++c) {
      const float4 hv = hp4[c];
      t = fmaf(hv.x, wa[4 * c + 0], t);
      t = fmaf(hv.y, wa[4 * c + 1], t);
      t = fmaf(hv.z, wa[4 * c + 2], t);
      t = fmaf(hv.w, wa[4 * c + 3], t);
    }
    t = fmaxf(t, 0.f);
    tsh[wv][lane] = t;
    float h = bb_l;
#pragma unroll
    for (int c = 0; c < 16; ++c) {
      const float4 tv = tp[c];
      h = fmaf(tv.x, wb[4 * c + 0], h);
      h = fmaf(tv.y, wb[4 * c + 1], h);
      h = fmaf(tv.z, wb[4 * c + 2], h);
      h = fmaf(tv.w, wb[4 * c + 3], h);
    }
    psum += h;
  }
  red[wv][lane] = psum;
  __syncthreads();
  if (threadIdx.x < 64) {
    const float s4 = red[0][lane] + red[1][lane] + red[2][lane] + red[3][lane];
    atomicAdd(&gsum[lane], s4);
  }
}

__global__ __launch_bounds__(256) void k_head(
    const float* __restrict__ gsum,
    const float* __restrict__ Wn1, const float* __restrict__ bn1,
    const float* __restrict__ Wn2, const float* __restrict__ bn2,
    const float* __restrict__ Ws1, const float* __restrict__ bs1,
    const float* __restrict__ Ws2, const float* __restrict__ bs2,
    const float* __restrict__ Wt1, const float* __restrict__ bt1,
    const float* __restrict__ Wt2, const float* __restrict__ bt2,
    float* __restrict__ out, float invN)
{
  __shared__ float g[64], z1[256], z2[128], sa[64], tb[64];
  const int t = threadIdx.x;
  if (t < 64) g[t] = gsum[t] * invN;
  __syncthreads();
  {
    float acc = bn1[t];
    for (int k = 0; k < 64; ++k) acc = fmaf(g[k], Wn1[k * 256 + t], acc);
    z1[t] = fmaxf(acc, 0.f);
  }
  __syncthreads();
  if (t < 128) {
    float acc = bn2[t];
    for (int k = 0; k < 256; ++k) acc = fmaf(z1[k], Wn2[k * 128 + t], acc);
    z2[t] = fmaxf(acc, 0.f);
  }
  __syncthreads();
  if (t < 64) {
    float acc = bs1[t];
    for (int k = 0; k < 128; ++k) acc = fmaf(z2[k], Ws1[k * 64 + t], acc);
    sa[t] = fmaxf(acc, 0.f);
  } else if (t < 128) {
    const int j = t - 64;
    float acc = bt1[j];
    for (int k = 0; k < 128; ++k) acc = fmaf(z2[k], Wt1[k * 64 + j], acc);
    tb[j] = fmaxf(acc, 0.f);
  }
  __syncthreads();
  if (t < 64) {
    float acc = bs2[t];
    for (int k = 0; k < 64; ++k) acc = fmaf(sa[k], Ws2[k * 64 + t], acc);
    out[t] = 1.f / (1.f + __expf(-acc));
  } else if (t < 96) {
    const int j = t - 64;
    float acc = bt2[j];
    for (int k = 0; k < 64; ++k) acc = fmaf(tb[k], Wt2[k * 32 + j], acc);
    out[64 + j] = 1.f / (1.f + __expf(-acc));
  }
}

// ================================ launch ===================================

extern "C" void kernel_launch(void* const* d_in, const int* in_sizes, int n_in,
                              void* d_out, int out_size, void* d_ws, size_t ws_size,
                              hipStream_t stream)
{
  const float* x   = (const float*)d_in[0];
  const float* ea  = (const float*)d_in[1];
  const int*   ei  = (const int*)d_in[2];
  const float* We1 = (const float*)d_in[3];  const float* be1 = (const float*)d_in[4];
  const float* W1a = (const float*)d_in[5];  const float* b1a = (const float*)d_in[6];
  const float* W1b = (const float*)d_in[7];  const float* b1b = (const float*)d_in[8];
  const float* We2 = (const float*)d_in[9];  const float* be2 = (const float*)d_in[10];
  const float* W2a = (const float*)d_in[11]; const float* b2a = (const float*)d_in[12];
  const float* W2b = (const float*)d_in[13]; const float* b2b = (const float*)d_in[14];
  const float* Wn1 = (const float*)d_in[15]; const float* bn1 = (const float*)d_in[16];
  const float* Wn2 = (const float*)d_in[17]; const float* bn2 = (const float*)d_in[18];
  const float* Ws1 = (const float*)d_in[19]; const float* bs1 = (const float*)d_in[20];
  const float* Ws2 = (const float*)d_in[21]; const float* bs2 = (const float*)d_in[22];
  const float* Wt1 = (const float*)d_in[23]; const float* bt1 = (const float*)d_in[24];
  const float* Wt2 = (const float*)d_in[25]; const float* bt2 = (const float*)d_in[26];

  const int N = in_sizes[0] / 32;
  const int E = in_sizes[1] / 16;
  const int* src = ei;
  const int* dst = ei + E;

  char* ws = (char*)d_ws;
  size_t off = 0;
  auto alloc = [&](size_t bytes) -> char* {
    char* p = ws + off;
    off = (off + bytes + 255) & ~(size_t)255;
    return p;
  };
  float* h1     = (float*)alloc((size_t)N * 64 * 4);
  float* aggr   = (float*)alloc((size_t)N * 64 * 4);
  float* gsum   = (float*)alloc(256);
  int*   count  = (int*)alloc((size_t)(N + 1) * 4);
  int*   start  = (int*)alloc((size_t)(N + 1) * 4);
  int*   cursor = (int*)alloc((size_t)(N + 1) * 4);
  int*   bsum   = (int*)alloc(4096);
  int*   perm   = (int*)alloc((size_t)E * 4);
  const size_t base_need = off;
  int*   srcs = (int*)alloc((size_t)E * 4);
  char*  easH = alloc((size_t)E * 32);              // bf16-packed [E][16]
  const size_t mat_need = off;

  const int mode = (ws_size >= mat_need) ? 2 : 1;
  (void)base_need;

  hipMemsetAsync(gsum, 0, 256, stream);

  const int M = N + 1;
  const int nb = (M + 1023) / 1024;
  const int egrid = min((E + 255) / 256, 8192);
  hipMemsetAsync(count, 0, (size_t)M * 4, stream);
  k_hist<<<egrid, 256, 0, stream>>>(dst, count, E);
  k_scan1<<<nb, 256, 0, stream>>>(count, start, bsum, M);
  k_scan2<<<1, 64, 0, stream>>>(bsum, nb);
  k_scan3<<<(M + 255) / 256, 256, 0, stream>>>(start, cursor, bsum, M);
  k_scatter_perm<<<egrid, 256, 0, stream>>>(dst, cursor, perm, E);
  if (mode == 2) {
    k_mat_bf<<<8192, 256, 0, stream>>>(perm, src, (const float4*)ea,
                                       srcs, (uint2*)easH, E);
    k_agg1_bf<<<2048, 256, 0, stream>>>(x, (const int4*)easH, srcs, start,
                                        We1, be1, aggr, N);
    k_node1<<<2048, 256, 0, stream>>>(x, aggr, W1a, b1a, W1b, b1b, h1, N);
    k_agg2_bf<<<2048, 256, 0, stream>>>(h1, (const int4*)easH, srcs, start,
                                        We2, be2, aggr, N);
  } else {
    k_agg1_f<<<2048, 256, 0, stream>>>(x, ea, src, perm, start, We1, be1, aggr, N);
    k_node1<<<2048, 256, 0, stream>>>(x, aggr, W1a, b1a, W1b, b1b, h1, N);
    k_agg2_f<<<2048, 256, 0, stream>>>(h1, ea, src, perm, start, We2, be2, aggr, N);
  }

  k_node2<<<2048, 256, 0, stream>>>(h1, aggr, W2a, b2a, W2b, b2b, gsum, N);
  k_head<<<1, 256, 0, stream>>>(gsum, Wn1, bn1, Wn2, bn2, Ws1, bs1, Ws2, bs2,
                                Wt1, bt1, Wt2, bt2, (float*)d_out, 1.f / (float)N);
}

// Round 11
// 817.842 us; speedup vs baseline: 1.3137x; 1.3137x over previous
//
#include <hip/hip_runtime.h>
#include <math.h>

// ---------------------------------------------------------------------------
// GINE 2-layer GNN, N=100K nodes (D 32->64->64), E=3.2M edges, ED=16.
// Round 11: R10's scatter split regressed (perm-scatter = 300us: 4B random
// stores still dirty 64B lines (16x WA) and 1-edge/thread has zero atomic
// ILP). Revert to R8's combined k_scatter_bf (199us proven: 4 lanes/edge,
// stores split across lanes). Keep R10's agg2@(256,8) (math==R8) and R8's
// agg1 (fp32 We1 per the layer-1 error-budget rule). Agg grids 2048->4096
// (2x oversubscription to fix degree-variance tail imbalance, occ 49%).
// ---------------------------------------------------------------------------

#define IMIN(a, b) ((a) < (b) ? (a) : (b))

__device__ __forceinline__ unsigned short f2bf(float f) {
  unsigned int u = __float_as_uint(f);
  u += 0x7FFFu + ((u >> 16) & 1u);
  return (unsigned short)(u >> 16);
}
__device__ __forceinline__ float bflo(int w) {
  return __uint_as_float(((unsigned int)w) << 16);
}
__device__ __forceinline__ float bfhi(int w) {
  return __uint_as_float(((unsigned int)w) & 0xFFFF0000u);
}
// D = a.bf16[0]*b.bf16[0] + a.bf16[1]*b.bf16[1] + c ; a is wave-uniform SGPR
__device__ __forceinline__ float dot2bf_s(unsigned a, unsigned b, float c) {
  float r;
  asm("v_dot2_f32_bf16 %0, %1, %2, %3" : "=v"(r) : "s"(a), "v"(b), "v"(c));
  return r;
}

// ============================ sort pipeline ================================

__global__ __launch_bounds__(256) void k_hist(
    const int* __restrict__ dst, int* __restrict__ count, int E)
{
  for (int e = blockIdx.x * blockDim.x + threadIdx.x; e < E;
       e += gridDim.x * blockDim.x)
    atomicAdd(&count[dst[e]], 1);
}

__global__ __launch_bounds__(256) void k_scan1(
    const int* __restrict__ cnt, int* __restrict__ exc,
    int* __restrict__ bsum, int M)
{
  __shared__ int wtot[4];
  const int t = threadIdx.x, lane = t & 63, wv = t >> 6;
  const int base = blockIdx.x * 1024 + t * 4;
  const int v0 = (base + 0 < M) ? cnt[base + 0] : 0;
  const int v1 = (base + 1 < M) ? cnt[base + 1] : 0;
  const int v2 = (base + 2 < M) ? cnt[base + 2] : 0;
  const int v3 = (base + 3 < M) ? cnt[base + 3] : 0;
  const int tsum = v0 + v1 + v2 + v3;
  int x = tsum;
#pragma unroll
  for (int off = 1; off < 64; off <<= 1) {
    const int y = __shfl_up(x, off, 64);
    if (lane >= off) x += y;
  }
  if (lane == 63) wtot[wv] = x;
  __syncthreads();
  int woff = 0;
#pragma unroll
  for (int w = 0; w < 4; ++w)
    if (w < wv) woff += wtot[w];
  int run = woff + x - tsum;
  if (base + 0 < M) exc[base + 0] = run;
  run += v0;
  if (base + 1 < M) exc[base + 1] = run;
  run += v1;
  if (base + 2 < M) exc[base + 2] = run;
  run += v2;
  if (base + 3 < M) exc[base + 3] = run;
  if (t == 255) bsum[blockIdx.x] = woff + x;
}

__global__ void k_scan2(int* __restrict__ bsum, int nb)
{
  if (threadIdx.x == 0) {
    int r = 0;
    for (int i = 0; i < nb; ++i) { const int t = bsum[i]; bsum[i] = r; r += t; }
  }
}

__global__ __launch_bounds__(256) void k_scan3(
    int* __restrict__ start, int* __restrict__ cursor,
    const int* __restrict__ bsum, int M)
{
  for (int i = blockIdx.x * blockDim.x + threadIdx.x; i < M;
       i += gridDim.x * blockDim.x) {
    const int s = start[i] + bsum[i >> 10];
    start[i] = s;
    cursor[i] = s;
  }
}

// combined scatter (R8): 4 threads/edge; leader grabs slot via atomic, pos
// broadcast by shfl; each sub converts 4 floats -> 4 bf16 and writes 8B.
__global__ __launch_bounds__(256) void k_scatter_bf(
    const int* __restrict__ src, const int* __restrict__ dst,
    const float4* __restrict__ ea4, int* __restrict__ cursor,
    int* __restrict__ srcs, uint2* __restrict__ easH, int E)
{
  const long tid0 = (long)blockIdx.x * blockDim.x + threadIdx.x;
  const long stride = (long)gridDim.x * blockDim.x;
  const int sub = threadIdx.x & 3;
  const long total = (long)E * 4;
  for (long t = tid0; t < total; t += stride) {
    const int e = (int)(t >> 2);
    int pos = 0;
    if (sub == 0) pos = atomicAdd(&cursor[dst[e]], 1);
    pos = __shfl(pos, 0, 4);
    if (sub == 0) srcs[pos] = src[e];
    const float4 v = ea4[(size_t)e * 4 + sub];
    uint2 w;
    w.x = (unsigned)f2bf(v.x) | ((unsigned)f2bf(v.y) << 16);
    w.y = (unsigned)f2bf(v.z) | ((unsigned)f2bf(v.w) << 16);
    easH[(size_t)pos * 4 + sub] = w;
  }
}

// mode-1 fallback scatter: perm tokens only
__global__ __launch_bounds__(256) void k_scatter_perm(
    const int* __restrict__ dst, int* __restrict__ cursor,
    int* __restrict__ perm, int E)
{
  for (int e = blockIdx.x * blockDim.x + threadIdx.x; e < E;
       e += gridDim.x * blockDim.x) {
    const int pos = atomicAdd(&cursor[dst[e]], 1);
    perm[pos] = e;
  }
}

// ============ fused edge-embed + aggregate (bf16 eas) ======================

// agg2: SGPR-fed v_dot2_f32_bf16 (We2 bf16 is in-budget), 8 waves/SIMD.
__global__ __launch_bounds__(256, 8) void k_agg2_bf(
    const float* __restrict__ h1, const int4* __restrict__ EH,
    const int* __restrict__ srcs, const int* __restrict__ start,
    const float* __restrict__ We, const float* __restrict__ be,
    float* __restrict__ aggr, int N)
{
  const int lane = threadIdx.x & 63;
  unsigned wcolp[8];
#pragma unroll
  for (int c = 0; c < 8; ++c)
    wcolp[c] = (unsigned)f2bf(We[(2 * c) * 64 + lane]) |
               ((unsigned)f2bf(We[(2 * c + 1) * 64 + lane]) << 16);
  const float bias = be[lane];
  const int wid = (blockIdx.x * blockDim.x + threadIdx.x) >> 6;
  const int nw = (gridDim.x * blockDim.x) >> 6;
  for (int d = wid; d < N; d += nw) {
    const int beg = __builtin_amdgcn_readfirstlane(start[d]);
    const int end = __builtin_amdgcn_readfirstlane(start[d + 1]);
    float acc = 0.f;
    if (beg < end) {
      const int em1 = end - 1;
      int4 evA[4][2], evB[4][2];
      float hvA[4], hvB[4];
      int sB[4], sC[4];
      {
        int sA[4];
#pragma unroll
        for (int q = 0; q < 4; ++q) {
          const int c = IMIN(beg + q, em1);
          sA[q] = srcs[c];
          evA[q][0] = EH[(size_t)c * 2 + 0];
          evA[q][1] = EH[(size_t)c * 2 + 1];
        }
#pragma unroll
        for (int q = 0; q < 4; ++q) hvA[q] = h1[(size_t)sA[q] * 64 + lane];
#pragma unroll
        for (int q = 0; q < 4; ++q) {
          const int c = IMIN(beg + 4 + q, em1);
          sB[q] = srcs[c];
        }
      }
      for (int i = beg; i < end; i += 4) {
        const bool inB = (i + 4) < end;
        if (inB) {
#pragma unroll
          for (int q = 0; q < 4; ++q) {
            const int c = IMIN(i + 4 + q, em1);
            evB[q][0] = EH[(size_t)c * 2 + 0];
            evB[q][1] = EH[(size_t)c * 2 + 1];
          }
#pragma unroll
          for (int q = 0; q < 4; ++q) hvB[q] = h1[(size_t)sB[q] * 64 + lane];
#pragma unroll
          for (int q = 0; q < 4; ++q) {
            const int c = IMIN(i + 8 + q, em1);
            sC[q] = srcs[c];
          }
        } else {
#pragma unroll
          for (int q = 0; q < 4; ++q) {
            evB[q][0] = evA[q][0]; evB[q][1] = evA[q][1];
            hvB[q] = hvA[q]; sC[q] = sB[q];
          }
        }
        __builtin_amdgcn_sched_barrier(0);
#pragma unroll
        for (int q = 0; q < 4; ++q) {
          const int4 w0 = evA[q][0], w1 = evA[q][1];
          float m = bias;
          m = dot2bf_s((unsigned)w0.x, wcolp[0], m);
          m = dot2bf_s((unsigned)w0.y, wcolp[1], m);
          m = dot2bf_s((unsigned)w0.z, wcolp[2], m);
          m = dot2bf_s((unsigned)w0.w, wcolp[3], m);
          m = dot2bf_s((unsigned)w1.x, wcolp[4], m);
          m = dot2bf_s((unsigned)w1.y, wcolp[5], m);
          m = dot2bf_s((unsigned)w1.z, wcolp[6], m);
          m = dot2bf_s((unsigned)w1.w, wcolp[7], m);
          acc += (i + q < end) ? fmaxf(hvA[q] + m, 0.f) : 0.f;
        }
#pragma unroll
        for (int q = 0; q < 4; ++q) {
          evA[q][0] = evB[q][0]; evA[q][1] = evB[q][1];
          hvA[q] = hvB[q]; sB[q] = sC[q];
        }
      }
    }
    aggr[(size_t)d * 64 + lane] = acc;
  }
}

// agg1: R8's proven kernel — fp32 We1 (layer-1 error budget), bf16 ea unpack,
// half-wave split, 8 edges/iter.
__global__ __launch_bounds__(256, 4) void k_agg1_bf(
    const float* __restrict__ x, const int4* __restrict__ EH,
    const int* __restrict__ srcs, const int* __restrict__ start,
    const float* __restrict__ We, const float* __restrict__ be,
    float* __restrict__ aggr, int N)
{
  const int lane = threadIdx.x & 63;
  const int j = lane & 31;
  const int o = (lane >> 5) * 4;  // half-wave chain base within 8-block
  float wcol[16];
#pragma unroll
  for (int k = 0; k < 16; ++k) wcol[k] = We[k * 32 + j];
  const float bias = be[j];
  const int wid = (blockIdx.x * blockDim.x + threadIdx.x) >> 6;
  const int nw = (gridDim.x * blockDim.x) >> 6;
  for (int d = wid; d < N; d += nw) {
    const int beg = __builtin_amdgcn_readfirstlane(start[d]);
    const int end = __builtin_amdgcn_readfirstlane(start[d + 1]);
    float acc = 0.f;
    if (beg < end) {
      const int em1 = end - 1;
      int4 evA[4][2], evB[4][2];
      float hvA[4], hvB[4];
      int sB[4], sC[4];
      {
        int sA[4];
#pragma unroll
        for (int q = 0; q < 4; ++q) {
          const int c = IMIN(beg + o + q, em1);
          sA[q] = srcs[c];
          evA[q][0] = EH[(size_t)c * 2 + 0];
          evA[q][1] = EH[(size_t)c * 2 + 1];
        }
#pragma unroll
        for (int q = 0; q < 4; ++q) hvA[q] = x[(size_t)sA[q] * 32 + j];
#pragma unroll
        for (int q = 0; q < 4; ++q) {
          const int c = IMIN(beg + 8 + o + q, em1);
          sB[q] = srcs[c];
        }
      }
      for (int i = beg; i < end; i += 8) {
        const bool inB = (i + 8) < end;
        if (inB) {
#pragma unroll
          for (int q = 0; q < 4; ++q) {
            const int c = IMIN(i + 8 + o + q, em1);
            evB[q][0] = EH[(size_t)c * 2 + 0];
            evB[q][1] = EH[(size_t)c * 2 + 1];
          }
#pragma unroll
          for (int q = 0; q < 4; ++q) hvB[q] = x[(size_t)sB[q] * 32 + j];
#pragma unroll
          for (int q = 0; q < 4; ++q) {
            const int c = IMIN(i + 16 + o + q, em1);
            sC[q] = srcs[c];
          }
        } else {
#pragma unroll
          for (int q = 0; q < 4; ++q) {
            evB[q][0] = evA[q][0]; evB[q][1] = evA[q][1];
            hvB[q] = hvA[q]; sC[q] = sB[q];
          }
        }
        __builtin_amdgcn_sched_barrier(0);
#pragma unroll
        for (int q = 0; q < 4; ++q) {
          const int4 w0 = evA[q][0], w1 = evA[q][1];
          float m = bias;
          m = fmaf(bflo(w0.x), wcol[0],  m); m = fmaf(bfhi(w0.x), wcol[1],  m);
          m = fmaf(bflo(w0.y), wcol[2],  m); m = fmaf(bfhi(w0.y), wcol[3],  m);
          m = fmaf(bflo(w0.z), wcol[4],  m); m = fmaf(bfhi(w0.z), wcol[5],  m);
          m = fmaf(bflo(w0.w), wcol[6],  m); m = fmaf(bfhi(w0.w), wcol[7],  m);
          m = fmaf(bflo(w1.x), wcol[8],  m); m = fmaf(bfhi(w1.x), wcol[9],  m);
          m = fmaf(bflo(w1.y), wcol[10], m); m = fmaf(bfhi(w1.y), wcol[11], m);
          m = fmaf(bflo(w1.z), wcol[12], m); m = fmaf(bfhi(w1.z), wcol[13], m);
          m = fmaf(bflo(w1.w), wcol[14], m); m = fmaf(bfhi(w1.w), wcol[15], m);
          acc += (i + o + q < end) ? fmaxf(hvA[q] + m, 0.f) : 0.f;
        }
#pragma unroll
        for (int q = 0; q < 4; ++q) {
          evA[q][0] = evB[q][0]; evA[q][1] = evB[q][1];
          hvA[q] = hvB[q]; sB[q] = sC[q];
        }
      }
    }
    acc += __shfl(acc, lane ^ 32, 64);
    if (lane < 32) aggr[(size_t)d * 32 + j] = acc;
  }
}

// ================= mode-1 fallback (fp32 ea via perm) ======================

__global__ __launch_bounds__(256, 4) void k_agg2_f(
    const float* __restrict__ h1, const float* __restrict__ EA,
    const int* __restrict__ SRCS, const int* __restrict__ perm,
    const int* __restrict__ start, const float* __restrict__ We,
    const float* __restrict__ be, float* __restrict__ aggr, int N)
{
  const int lane = threadIdx.x & 63;
  float wcol[16];
#pragma unroll
  for (int k = 0; k < 16; ++k) wcol[k] = We[k * 64 + lane];
  const float bias = be[lane];
  const float4* EA4 = (const float4*)EA;
  const int wid = (blockIdx.x * blockDim.x + threadIdx.x) >> 6;
  const int nw = (gridDim.x * blockDim.x) >> 6;
  for (int d = wid; d < N; d += nw) {
    const int beg = __builtin_amdgcn_readfirstlane(start[d]);
    const int end = __builtin_amdgcn_readfirstlane(start[d + 1]);
    float acc = 0.f;
    for (int i = beg; i < end; ++i) {
      const int a = perm[i];
      const int s = SRCS[a];
      float4 ev[4];
#pragma unroll
      for (int c = 0; c < 4; ++c) ev[c] = EA4[(size_t)a * 4 + c];
      const float hv = h1[(size_t)s * 64 + lane];
      float m = bias;
#pragma unroll
      for (int c = 0; c < 4; ++c) {
        m = fmaf(ev[c].x, wcol[4 * c + 0], m);
        m = fmaf(ev[c].y, wcol[4 * c + 1], m);
        m = fmaf(ev[c].z, wcol[4 * c + 2], m);
        m = fmaf(ev[c].w, wcol[4 * c + 3], m);
      }
      acc += fmaxf(hv + m, 0.f);
    }
    aggr[(size_t)d * 64 + lane] = acc;
  }
}

__global__ __launch_bounds__(256, 4) void k_agg1_f(
    const float* __restrict__ x, const float* __restrict__ EA,
    const int* __restrict__ SRCS, const int* __restrict__ perm,
    const int* __restrict__ start, const float* __restrict__ We,
    const float* __restrict__ be, float* __restrict__ aggr, int N)
{
  const int lane = threadIdx.x & 63;
  const int j = lane & 31;
  const int p = lane >> 5;
  float wcol[16];
#pragma unroll
  for (int k = 0; k < 16; ++k) wcol[k] = We[k * 32 + j];
  const float bias = be[j];
  const float4* EA4 = (const float4*)EA;
  const int wid = (blockIdx.x * blockDim.x + threadIdx.x) >> 6;
  const int nw = (gridDim.x * blockDim.x) >> 6;
  for (int d = wid; d < N; d += nw) {
    const int beg = __builtin_amdgcn_readfirstlane(start[d]);
    const int end = __builtin_amdgcn_readfirstlane(start[d + 1]);
    float acc = 0.f;
    for (int i = beg + p; i < end; i += 2) {
      const int a = perm[i];
      const int s = SRCS[a];
      float4 ev[4];
#pragma unroll
      for (int c = 0; c < 4; ++c) ev[c] = EA4[(size_t)a * 4 + c];
      const float xv = x[(size_t)s * 32 + j];
      float m = bias;
#pragma unroll
      for (int c = 0; c < 4; ++c) {
        m = fmaf(ev[c].x, wcol[4 * c + 0], m);
        m = fmaf(ev[c].y, wcol[4 * c + 1], m);
        m = fmaf(ev[c].z, wcol[4 * c + 2], m);
        m = fmaf(ev[c].w, wcol[4 * c + 3], m);
      }
      acc += fmaxf(xv + m, 0.f);
    }
    acc += __shfl(acc, lane ^ 32, 64);
    if (lane < 32) aggr[(size_t)d * 32 + j] = acc;
  }
}

// ============================ node MLPs + head =============================

__global__ __launch_bounds__(256) void k_node1(
    const float* __restrict__ x, const float* __restrict__ aggr,
    const float* __restrict__ Wa, const float* __restrict__ ba,
    const float* __restrict__ Wb, const float* __restrict__ bb,
    float* __restrict__ h1, int N)
{
  __shared__ float hsh[4][32];
  __shared__ float tsh[4][64];
  const int lane = threadIdx.x & 63;
  const int wv = threadIdx.x >> 6;
  float wa[32], wb[64];
#pragma unroll
  for (int k = 0; k < 32; ++k) wa[k] = Wa[k * 64 + lane];
#pragma unroll
  for (int k = 0; k < 64; ++k) wb[k] = Wb[k * 64 + lane];
  const float ba_l = ba[lane], bb_l = bb[lane];
  const int wid = (blockIdx.x * blockDim.x + threadIdx.x) >> 6;
  const int nw = (gridDim.x * blockDim.x) >> 6;
  const float4* hp4 = (const float4*)(&hsh[wv][0]);
  const float4* tp = (const float4*)(&tsh[wv][0]);
  for (int n = wid; n < N; n += nw) {
    if (lane < 32)
      hsh[wv][lane] = x[(size_t)n * 32 + lane] + aggr[(size_t)n * 32 + lane];
    float t = ba_l;
#pragma unroll
    for (int c = 0; c < 8; ++c) {
      const float4 hv = hp4[c];
      t = fmaf(hv.x, wa[4 * c + 0], t);
      t = fmaf(hv.y, wa[4 * c + 1], t);
      t = fmaf(hv.z, wa[4 * c + 2], t);
      t = fmaf(hv.w, wa[4 * c + 3], t);
    }
    t = fmaxf(t, 0.f);
    tsh[wv][lane] = t;
    float h = bb_l;
#pragma unroll
    for (int c = 0; c < 16; ++c) {
      const float4 tv = tp[c];
      h = fmaf(tv.x, wb[4 * c + 0], h);
      h = fmaf(tv.y, wb[4 * c + 1], h);
      h = fmaf(tv.z, wb[4 * c + 2], h);
      h = fmaf(tv.w, wb[4 * c + 3], h);
    }
    h1[(size_t)n * 64 + lane] = h;
  }
}

__global__ __launch_bounds__(256) void k_node2(
    const float* __restrict__ h1, const float* __restrict__ aggr,
    const float* __restrict__ Wa, const float* __restrict__ ba,
    const float* __restrict__ Wb, const float* __restrict__ bb,
    float* __restrict__ gsum, int N)
{
  __shared__ float hsh[4][64];
  __shared__ float tsh[4][64];
  __shared__ float red[4][64];
  const int lane = threadIdx.x & 63;
  const int wv = threadIdx.x >> 6;
  float wa[64], wb[64];
#pragma unroll
  for (int k = 0; k < 64; ++k) wa[k] = Wa[k * 64 + lane];
#pragma unroll
  for (int k = 0; k < 64; ++k) wb[k] = Wb[k * 64 + lane];
  const float ba_l = ba[lane], bb_l = bb[lane];
  float psum = 0.f;
  const int wid = (blockIdx.x * blockDim.x + threadIdx.x) >> 6;
  const int nw = (gridDim.x * blockDim.x) >> 6;
  const float4* hp4 = (const float4*)(&hsh[wv][0]);
  const float4* tp = (const float4*)(&tsh[wv][0]);
  for (int n = wid; n < N; n += nw) {
    hsh[wv][lane] = h1[(size_t)n * 64 + lane] + aggr[(size_t)n * 64 + lane];
    float t = ba_l;
#pragma unroll
    for (int c = 0; c < 16; ++c) {
      const float4 hv = hp4[c];
      t = fmaf(hv.x, wa[4 * c + 0], t);
      t = fmaf(hv.y, wa[4 * c + 1], t);
      t = fmaf(hv.z, wa[4 * c + 2], t);
      t = fmaf(hv.w, wa[4 * c + 3], t);
    }
    t = fmaxf(t, 0.f);
    tsh[wv][lane] = t;
    float h = bb_l;
#pragma unroll
    for (int c = 0; c < 16; ++c) {
      const float4 tv = tp[c];
      h = fmaf(tv.x, wb[4 * c + 0], h);
      h = fmaf(tv.y, wb[4 * c + 1], h);
      h = fmaf(tv.z, wb[4 * c + 2], h);
      h = fmaf(tv.w, wb[4 * c + 3], h);
    }
    psum += h;
  }
  red[wv][lane] = psum;
  __syncthreads();
  if (threadIdx.x < 64) {
    const float s4 = red[0][lane] + red[1][lane] + red[2][lane] + red[3][lane];
    atomicAdd(&gsum[lane], s4);
  }
}

__global__ __launch_bounds__(256) void k_head(
    const float* __restrict__ gsum,
    const float* __restrict__ Wn1, const float* __restrict__ bn1,
    const float* __restrict__ Wn2, const float* __restrict__ bn2,
    const float* __restrict__ Ws1, const float* __restrict__ bs1,
    const float* __restrict__ Ws2, const float* __restrict__ bs2,
    const float* __restrict__ Wt1, const float* __restrict__ bt1,
    const float* __restrict__ Wt2, const float* __restrict__ bt2,
    float* __restrict__ out, float invN)
{
  __shared__ float g[64], z1[256], z2[128], sa[64], tb[64];
  const int t = threadIdx.x;
  if (t < 64) g[t] = gsum[t] * invN;
  __syncthreads();
  {
    float acc = bn1[t];
    for (int k = 0; k < 64; ++k) acc = fmaf(g[k], Wn1[k * 256 + t], acc);
    z1[t] = fmaxf(acc, 0.f);
  }
  __syncthreads();
  if (t < 128) {
    float acc = bn2[t];
    for (int k = 0; k < 256; ++k) acc = fmaf(z1[k], Wn2[k * 128 + t], acc);
    z2[t] = fmaxf(acc, 0.f);
  }
  __syncthreads();
  if (t < 64) {
    float acc = bs1[t];
    for (int k = 0; k < 128; ++k) acc = fmaf(z2[k], Ws1[k * 64 + t], acc);
    sa[t] = fmaxf(acc, 0.f);
  } else if (t < 128) {
    const int j = t - 64;
    float acc = bt1[j];
    for (int k = 0; k < 128; ++k) acc = fmaf(z2[k], Wt1[k * 64 + j], acc);
    tb[j] = fmaxf(acc, 0.f);
  }
  __syncthreads();
  if (t < 64) {
    float acc = bs2[t];
    for (int k = 0; k < 64; ++k) acc = fmaf(sa[k], Ws2[k * 64 + t], acc);
    out[t] = 1.f / (1.f + __expf(-acc));
  } else if (t < 96) {
    const int j = t - 64;
    float acc = bt2[j];
    for (int k = 0; k < 64; ++k) acc = fmaf(tb[k], Wt2[k * 32 + j], acc);
    out[64 + j] = 1.f / (1.f + __expf(-acc));
  }
}

// ================================ launch ===================================

extern "C" void kernel_launch(void* const* d_in, const int* in_sizes, int n_in,
                              void* d_out, int out_size, void* d_ws, size_t ws_size,
                              hipStream_t stream)
{
  const float* x   = (const float*)d_in[0];
  const float* ea  = (const float*)d_in[1];
  const int*   ei  = (const int*)d_in[2];
  const float* We1 = (const float*)d_in[3];  const float* be1 = (const float*)d_in[4];
  const float* W1a = (const float*)d_in[5];  const float* b1a = (const float*)d_in[6];
  const float* W1b = (const float*)d_in[7];  const float* b1b = (const float*)d_in[8];
  const float* We2 = (const float*)d_in[9];  const float* be2 = (const float*)d_in[10];
  const float* W2a = (const float*)d_in[11]; const float* b2a = (const float*)d_in[12];
  const float* W2b = (const float*)d_in[13]; const float* b2b = (const float*)d_in[14];
  const float* Wn1 = (const float*)d_in[15]; const float* bn1 = (const float*)d_in[16];
  const float* Wn2 = (const float*)d_in[17]; const float* bn2 = (const float*)d_in[18];
  const float* Ws1 = (const float*)d_in[19]; const float* bs1 = (const float*)d_in[20];
  const float* Ws2 = (const float*)d_in[21]; const float* bs2 = (const float*)d_in[22];
  const float* Wt1 = (const float*)d_in[23]; const float* bt1 = (const float*)d_in[24];
  const float* Wt2 = (const float*)d_in[25]; const float* bt2 = (const float*)d_in[26];

  const int N = in_sizes[0] / 32;
  const int E = in_sizes[1] / 16;
  const int* src = ei;
  const int* dst = ei + E;

  char* ws = (char*)d_ws;
  size_t off = 0;
  auto alloc = [&](size_t bytes) -> char* {
    char* p = ws + off;
    off = (off + bytes + 255) & ~(size_t)255;
    return p;
  };
  float* h1     = (float*)alloc((size_t)N * 64 * 4);
  float* aggr   = (float*)alloc((size_t)N * 64 * 4);
  float* gsum   = (float*)alloc(256);
  int*   count  = (int*)alloc((size_t)(N + 1) * 4);
  int*   start  = (int*)alloc((size_t)(N + 1) * 4);
  int*   cursor = (int*)alloc((size_t)(N + 1) * 4);
  int*   bsum   = (int*)alloc(4096);
  int*   perm   = (int*)alloc((size_t)E * 4);
  const size_t base_need = off;
  int*   srcs = (int*)alloc((size_t)E * 4);
  char*  easH = alloc((size_t)E * 32);              // bf16-packed [E][16]
  const size_t mat_need = off;

  const int mode = (ws_size >= mat_need) ? 2 : 1;
  (void)base_need;

  hipMemsetAsync(gsum, 0, 256, stream);

  const int M = N + 1;
  const int nb = (M + 1023) / 1024;
  const int egrid = min((E + 255) / 256, 8192);
  hipMemsetAsync(count, 0, (size_t)M * 4, stream);
  k_hist<<<egrid, 256, 0, stream>>>(dst, count, E);
  k_scan1<<<nb, 256, 0, stream>>>(count, start, bsum, M);
  k_scan2<<<1, 64, 0, stream>>>(bsum, nb);
  k_scan3<<<(M + 255) / 256, 256, 0, stream>>>(start, cursor, bsum, M);
  if (mode == 2) {
    k_scatter_bf<<<8192, 256, 0, stream>>>(src, dst, (const float4*)ea,
                                           cursor, srcs, (uint2*)easH, E);
    k_agg1_bf<<<4096, 256, 0, stream>>>(x, (const int4*)easH, srcs, start,
                                        We1, be1, aggr, N);
    k_node1<<<2048, 256, 0, stream>>>(x, aggr, W1a, b1a, W1b, b1b, h1, N);
    k_agg2_bf<<<4096, 256, 0, stream>>>(h1, (const int4*)easH, srcs, start,
                                        We2, be2, aggr, N);
  } else {
    k_scatter_perm<<<egrid, 256, 0, stream>>>(dst, cursor, perm, E);
    k_agg1_f<<<4096, 256, 0, stream>>>(x, ea, src, perm, start, We1, be1, aggr, N);
    k_node1<<<2048, 256, 0, stream>>>(x, aggr, W1a, b1a, W1b, b1b, h1, N);
    k_agg2_f<<<4096, 256, 0, stream>>>(h1, ea, src, perm, start, We2, be2, aggr, N);
  }

  k_node2<<<2048, 256, 0, stream>>>(h1, aggr, W2a, b2a, W2b, b2b, gsum, N);
  k_head<<<1, 256, 0, stream>>>(gsum, Wn1, bn1, Wn2, bn2, Ws1, bs1, Ws2, bs2,
                                Wt1, bt1, Wt2, bt2, (float*)d_out, 1.f / (float)N);
}